// Round 6
// baseline (324.320 us; speedup 1.0000x reference)
//
#include <hip/hip_runtime.h>
#include <stdint.h>

#define TTOK 4096
#define DM   1024
#define FF   2048
#define NE   8
#define SHSEG 10240          // fixed base of shared-expert rows in H (max padded routed = 10240)
#define HROWS 14336          // SHSEG + TTOK

typedef __attribute__((ext_vector_type(8))) short short8;
typedef __attribute__((ext_vector_type(8))) unsigned short ushort8;
typedef __attribute__((ext_vector_type(4))) float f32x4;

// ---------------- workspace layout (bytes) ----------------
#define OFF_XB      0ull
#define OFF_WB13    (OFF_XB      + (size_t)TTOK*DM*2)
#define OFF_WB2     (OFF_WB13    + (size_t)9*4096*1024*2)
#define OFF_H       (OFF_WB2     + (size_t)9*1024*2048*2)
#define OFF_CONTRIB OFF_WB13     // overlay: wb13 dead after g13; contrib 40MB < wb13 75MB
#define OFF_TOPKW   (OFF_H       + (size_t)HROWS*2048*2)
#define OFF_TOPKI   (OFF_TOPKW   + (size_t)TTOK*2*4)
#define OFF_SLOTTOK (OFF_TOPKI   + (size_t)TTOK*2*4)
#define OFF_TOKSLOT (OFF_SLOTTOK + (size_t)SHSEG*4)
#define OFF_OFFS    (OFF_TOKSLOT + (size_t)TTOK*2*4)
#define WS_NEEDED   (OFF_OFFS + 64)

#define VMWAIT(N) asm volatile("s_waitcnt vmcnt(" #N ")" ::: "memory")
#define LGKM0()   asm volatile("s_waitcnt lgkmcnt(0)" ::: "memory")
#define BAR()     __builtin_amdgcn_s_barrier()
#define SCHED0()  __builtin_amdgcn_sched_barrier(0)

__device__ __forceinline__ unsigned short f2bf(float f) {
  unsigned u = __float_as_uint(f);
  return (unsigned short)((u + 0x7FFFu + ((u >> 16) & 1u)) >> 16);
}

__device__ __forceinline__ void async16(const void* g, void* l) {
  __builtin_amdgcn_global_load_lds(
      (const __attribute__((address_space(1))) void*)g,
      (__attribute__((address_space(3))) void*)l, 16, 0, 0);
}

// ---------------- gate (fp32) + x->bf16 convert ----------------
__global__ void k_gatecvt(const float* __restrict__ x, const float* __restrict__ Wg,
                          float* __restrict__ topkw, int* __restrict__ topki,
                          unsigned short* __restrict__ xb) {
  int wave = threadIdx.x >> 6;
  int lane = threadIdx.x & 63;
  int t = blockIdx.x * 4 + wave;
  float acc[NE];
#pragma unroll
  for (int e = 0; e < NE; e++) acc[e] = 0.f;
  const float* xr = x + (size_t)t * DM;
  unsigned short* xbr = xb + (size_t)t * DM;
#pragma unroll
  for (int i = 0; i < 4; i++) {
    int k = i * 256 + lane * 4;
    f32x4 xv = *(const f32x4*)(xr + k);
    unsigned short o0 = f2bf(xv[0]), o1 = f2bf(xv[1]), o2 = f2bf(xv[2]), o3 = f2bf(xv[3]);
    unsigned long long pk = (unsigned long long)o0 | ((unsigned long long)o1 << 16) |
                            ((unsigned long long)o2 << 32) | ((unsigned long long)o3 << 48);
    *(unsigned long long*)(xbr + k) = pk;
#pragma unroll
    for (int j = 0; j < 4; j++) {
      const float* wr = Wg + (size_t)(k + j) * NE;
#pragma unroll
      for (int e = 0; e < NE; e++) acc[e] += xv[j] * wr[e];
    }
  }
#pragma unroll
  for (int e = 0; e < NE; e++) {
#pragma unroll
    for (int off = 32; off >= 1; off >>= 1) acc[e] += __shfl_xor(acc[e], off, 64);
  }
  if (lane == 0) {
    float g[NE];
#pragma unroll
    for (int e = 0; e < NE; e++) g[e] = 1.f / (1.f + __expf(-acc[e]));
    int i1 = -1, i2 = -1;
    float m1 = -1e30f, m2 = -1e30f;
#pragma unroll
    for (int e = 0; e < NE; e++) {
      float v = g[e];
      if (v > m1) { m2 = m1; i2 = i1; m1 = v; i1 = e; }
      else if (v > m2) { m2 = v; i2 = e; }
    }
    float s = m1 + m2;
    topkw[t * 2 + 0] = m1 / s;
    topkw[t * 2 + 1] = m2 / s;
    topki[t * 2 + 0] = i1;
    topki[t * 2 + 1] = i2;
  }
}

// single block: count, 256-aligned prefix, scatter; offs_g[8] = padded total PT
__global__ void k_route(const int* __restrict__ topki, int* __restrict__ offs_g,
                        int* __restrict__ slot_token, int* __restrict__ token_slot) {
  __shared__ int cnt[NE], off[NE], fill[NE];
  int tid = threadIdx.x;
  if (tid < NE) { cnt[tid] = 0; fill[tid] = 0; }
  __syncthreads();
  for (int t = tid; t < TTOK; t += 1024) {
    atomicAdd(&cnt[topki[t * 2 + 0]], 1);
    atomicAdd(&cnt[topki[t * 2 + 1]], 1);
  }
  __syncthreads();
  if (tid == 0) {
    int s = 0;
    for (int e = 0; e < NE; e++) { off[e] = s; s += (cnt[e] + 255) & ~255; }
    offs_g[8] = s;
  }
  __syncthreads();
  if (tid < NE) offs_g[tid] = off[tid];
  for (int s = tid; s < SHSEG; s += 1024) slot_token[s] = 0;   // pad slots -> token 0
  __syncthreads();
  for (int t = tid; t < TTOK; t += 1024) {
#pragma unroll
    for (int k = 0; k < 2; k++) {
      int e = topki[t * 2 + k];
      int pos = atomicAdd(&fill[e], 1);
      int slot = off[e] + pos;
      slot_token[slot] = t;
      token_slot[t * 2 + k] = slot;
    }
  }
}

// ---------------- vectorized 64x64 transposes ----------------
__global__ void k_t13(const float* __restrict__ We1, const float* __restrict__ We3,
                      const float* __restrict__ Ws1, const float* __restrict__ Ws3,
                      unsigned short* __restrict__ wb13) {
  __shared__ float tile[64][68];
  int z = blockIdx.z;
  unsigned short* dst = wb13 + (size_t)z * 4096 * 1024;
  int r0 = blockIdx.y * 64;
  int c0 = blockIdx.x * 64;
  int tid = threadIdx.x;
  int r = tid >> 2, q = tid & 3;
  int nn = tid >> 2, g = tid & 3;

  const float* srcs[2] = {(blockIdx.z < 8) ? We1 + (size_t)z * DM * FF : Ws1,
                          (blockIdx.z < 8) ? We3 + (size_t)z * DM * FF : Ws3};
#pragma unroll
  for (int m = 0; m < 2; m++) {
    const float* src = srcs[m] + (size_t)(r0 + r) * FF + c0;
#pragma unroll
    for (int i = 0; i < 4; i++)
      *(f32x4*)&tile[r][i * 16 + q * 4] = *(const f32x4*)(src + i * 16 + q * 4);
    __syncthreads();
    int n = c0 + nn;
    int d = ((n >> 4) << 5) + (n & 15) + m * 16;
    ushort8 o0, o1;
#pragma unroll
    for (int j = 0; j < 8; j++) o0[j] = f2bf(tile[g * 16 + j][nn]);
#pragma unroll
    for (int j = 0; j < 8; j++) o1[j] = f2bf(tile[g * 16 + 8 + j][nn]);
    unsigned short* dp = dst + (size_t)d * 1024 + r0 + g * 16;
    *(ushort8*)dp = o0;
    *(ushort8*)(dp + 8) = o1;
    __syncthreads();
  }
}

__global__ void k_t2(const float* __restrict__ We2, const float* __restrict__ Ws2,
                     unsigned short* __restrict__ wb2) {
  __shared__ float tile[64][68];
  int z = blockIdx.z;
  const float* src0 = (z < 8) ? We2 + (size_t)z * FF * DM : Ws2;
  unsigned short* dst = wb2 + (size_t)z * 1024 * 2048;
  int r0 = blockIdx.y * 64;
  int c0 = blockIdx.x * 64;
  int tid = threadIdx.x;
  int r = tid >> 2, q = tid & 3;
  int nn = tid >> 2, g = tid & 3;

  const float* src = src0 + (size_t)(r0 + r) * DM + c0;
#pragma unroll
  for (int i = 0; i < 4; i++)
    *(f32x4*)&tile[r][i * 16 + q * 4] = *(const f32x4*)(src + i * 16 + q * 4);
  __syncthreads();
  ushort8 o0, o1;
#pragma unroll
  for (int j = 0; j < 8; j++) o0[j] = f2bf(tile[g * 16 + j][nn]);
#pragma unroll
  for (int j = 0; j < 8; j++) o1[j] = f2bf(tile[g * 16 + 8 + j][nn]);
  unsigned short* dp = dst + (size_t)(c0 + nn) * 2048 + r0 + g * 16;
  *(ushort8*)dp = o0;
  *(ushort8*)(dp + 8) = o1;
}

// ---------------- 256x256 8-phase GEMM, BK=64, deep-slack calendar (vmcnt 6) ----------------
// Stage units: A in 4 row-stripe units/tile (8KiB: rows {u*32..+31} of both halves), B in 2 halves.
// Per iter (compute tiles 2I,2I+1):  P1: A(2I+1)u2,u3 | P2/P3: B(2I+2)h0,h1 | P4: A(2I+2)u0,u1
// +vmcnt(6)+preread B(2I+1) | P5: A(2I+2)u2,u3 | P6/P7: B(2I+3) | P8: A(2I+3)u0,u1+vmcnt(6)+preread.
// Every staged load has >=3 phases before its wait. Write-after-read verified per unit.
template <bool G13, int K, int NBROW>
__global__ __launch_bounds__(512, 2) void k_gemm(
    const unsigned short* __restrict__ A, const unsigned short* __restrict__ B,
    unsigned short* __restrict__ Hout, float* __restrict__ Cout, float* __restrict__ Dout,
    const int* __restrict__ slot_token, const int* __restrict__ offs) {
  __shared__ unsigned short As[2][256 * 64];        // 2 x 32 KiB
  __shared__ unsigned short Bs[2][2][128 * 64];     // 2 x 2 x 16 KiB
  const int NT = K / 64;

  int my = blockIdx.y;
  bool shd = (my >= 40);
  int base = (shd ? my - 40 : my) * 256;
  int e = 8;
  if (!shd) {
    if (base >= offs[8]) return;                    // beyond padded routed total
    e = 0;
    while (e < 7 && base >= offs[e + 1]) ++e;
  }
  int bn = blockIdx.x;
  int tid = threadIdx.x, lane = tid & 63, w = tid >> 6;

  // staging source byte-offsets (u32), XOR slot swizzle: src slot = (tid&7)^(row&7)
  int srcslot = (((tid & 7) ^ ((tid >> 3) & 7)) << 4);
  unsigned aoff[4];
#pragma unroll
  for (int u = 0; u < 4; u++) {
    int rl = u * 32 + (w & 3) * 8 + ((w >> 2) << 7) + (lane >> 3);
    long row;
    if (G13) row = shd ? (long)(base + rl) : (long)slot_token[base + rl];
    else     row = (long)((shd ? SHSEG : 0) + base + rl);
    aoff[u] = (unsigned)((size_t)row * K * 2) + srcslot;
  }
  unsigned boff[2];
#pragma unroll
  for (int half = 0; half < 2; half++) {
    int br = bn * 256 + half * 128 + (tid >> 3);
    boff[half] = (unsigned)(((size_t)e * NBROW + br) * K * 2) + srcslot;
  }
  const char* Abase = (const char*)A;
  const char* Bbase = (const char*)B;

#define A_STG(b, u, kt) \
  async16(Abase + aoff[u] + (kt) * 128, \
          &As[b][((u) * 32 + (w & 3) * 8 + ((w >> 2) << 7)) * 64])
#define B_STG(b, half, kt) do { \
    async16(Bbase + boff[half] + (size_t)(kt) * 128, &Bs[b][half][(w * 8) * 64]); \
    async16(Bbase + boff[half] + (size_t)64 * K * 2 + (size_t)(kt) * 128, \
            &Bs[b][half][(64 + w * 8) * 64]); \
  } while (0)

  // read-side bases
  int wr = w >> 2, wc = w & 3, wch = wc >> 1;
  const char* LA0 = (const char*)&As[0][0] + (wr * 128 + (lane & 15)) * 128;
  const char* LA1 = (const char*)&As[1][0] + (wr * 128 + (lane & 15)) * 128;
  const char* LB0 = (const char*)&Bs[0][wch][0] + ((wc & 1) * 64 + (lane & 15)) * 128;
  const char* LB1 = (const char*)&Bs[1][wch][0] + ((wc & 1) * 64 + (lane & 15)) * 128;
  int s0 = (((lane >> 4) ^ (lane & 7)) << 4);
  int s1 = (((4 + (lane >> 4)) ^ (lane & 7)) << 4);

  f32x4 acc[8][4];
#pragma unroll
  for (int i = 0; i < 8; i++)
#pragma unroll
    for (int j = 0; j < 4; j++) acc[i][j] = (f32x4){0.f, 0.f, 0.f, 0.f};

  short8 Bf[4][2];

#define PREREAD(LBx) do { \
    _Pragma("unroll") for (int nf = 0; nf < 4; nf++) { \
      Bf[nf][0] = *(const short8*)((LBx) + nf * 2048 + s0); \
      Bf[nf][1] = *(const short8*)((LBx) + nf * 2048 + s1); \
    } \
  } while (0)

#define PHASE(LAx, q, STGS, TAIL) do { \
    short8 Af0k0 = *(const short8*)((LAx) + ((q) * 2 + 0) * 2048 + s0); \
    short8 Af0k1 = *(const short8*)((LAx) + ((q) * 2 + 0) * 2048 + s1); \
    short8 Af1k0 = *(const short8*)((LAx) + ((q) * 2 + 1) * 2048 + s0); \
    short8 Af1k1 = *(const short8*)((LAx) + ((q) * 2 + 1) * 2048 + s1); \
    STGS; \
    BAR(); LGKM0(); SCHED0(); \
    __builtin_amdgcn_s_setprio(1); \
    _Pragma("unroll") for (int nf = 0; nf < 4; nf++) { \
      acc[(q) * 2 + 0][nf] = __builtin_amdgcn_mfma_f32_16x16x32_bf16(Af0k0, Bf[nf][0], acc[(q) * 2 + 0][nf], 0, 0, 0); \
      acc[(q) * 2 + 0][nf] = __builtin_amdgcn_mfma_f32_16x16x32_bf16(Af0k1, Bf[nf][1], acc[(q) * 2 + 0][nf], 0, 0, 0); \
      acc[(q) * 2 + 1][nf] = __builtin_amdgcn_mfma_f32_16x16x32_bf16(Af1k0, Bf[nf][0], acc[(q) * 2 + 1][nf], 0, 0, 0); \
      acc[(q) * 2 + 1][nf] = __builtin_amdgcn_mfma_f32_16x16x32_bf16(Af1k1, Bf[nf][1], acc[(q) * 2 + 1][nf], 0, 0, 0); \
    } \
    __builtin_amdgcn_s_setprio(0); \
    TAIL; \
    BAR(); \
  } while (0)

  // prologue: tiles 0 (all), 1 (B + A u0,u1); order mimics steady-state outstanding set
  B_STG(0, 0, 0); B_STG(0, 1, 0);
  A_STG(0, 0, 0); A_STG(0, 1, 0); A_STG(0, 2, 0); A_STG(0, 3, 0);
  B_STG(1, 0, 1); B_STG(1, 1, 1);
  A_STG(1, 0, 1); A_STG(1, 1, 1);
  VMWAIT(6);
  BAR();
  PREREAD(LB0);

  const int NIT = NT / 2;
  for (int it = 0; it < NIT; ++it) {
    int kt1 = 2 * it + 1;
    int kt2 = 2 * it + 2; if (kt2 > NT - 1) kt2 = NT - 1;   // tail over-stage: retired regions only
    int kt3 = 2 * it + 3; if (kt3 > NT - 1) kt3 = NT - 1;
    PHASE(LA0, 0, { A_STG(1, 2, kt1); A_STG(1, 3, kt1); }, {});
    PHASE(LA0, 1, { B_STG(0, 0, kt2); }, {});
    PHASE(LA0, 2, { B_STG(0, 1, kt2); }, {});
    PHASE(LA0, 3, { A_STG(0, 0, kt2); A_STG(0, 1, kt2); }, { VMWAIT(6); PREREAD(LB1); });
    PHASE(LA1, 0, { A_STG(0, 2, kt2); A_STG(0, 3, kt2); }, {});
    PHASE(LA1, 1, { B_STG(1, 0, kt3); }, {});
    PHASE(LA1, 2, { B_STG(1, 1, kt3); }, {});
    PHASE(LA1, 3, { A_STG(1, 0, kt3); A_STG(1, 1, kt3); }, { VMWAIT(6); PREREAD(LB0); });
  }
  VMWAIT(0);
#undef PHASE
#undef PREREAD
#undef A_STG
#undef B_STG

  // ---------------- epilogue (no guards: padded slot space) ----------------
  if (G13) {
    size_t hbase = (size_t)(shd ? SHSEG : 0) + base;
#pragma unroll
    for (int mi = 0; mi < 8; mi++)
#pragma unroll
      for (int j = 0; j < 2; j++)
#pragma unroll
        for (int q = 0; q < 4; q++) {
          int rl = wr * 128 + mi * 16 + (lane >> 4) * 4 + q;
          float v1 = acc[mi][2 * j][q], v3 = acc[mi][2 * j + 1][q];
          float h = (v1 / (1.f + __expf(-v1))) * v3;
          int ffcol = (bn * 8 + wc * 2 + j) * 16 + (lane & 15);
          Hout[(hbase + rl) * 2048 + ffcol] = f2bf(h);
        }
  } else {
#pragma unroll
    for (int mi = 0; mi < 8; mi++)
#pragma unroll
      for (int nf = 0; nf < 4; nf++)
#pragma unroll
        for (int q = 0; q < 4; q++) {
          int rl = wr * 128 + mi * 16 + (lane >> 4) * 4 + q;
          int col = bn * 256 + wc * 64 + nf * 16 + (lane & 15);
          if (shd) Dout[(size_t)(base + rl) * 1024 + col] = acc[mi][nf][q];
          else     Cout[(size_t)(base + rl) * 1024 + col] = acc[mi][nf][q];
        }
  }
}

// out[t] = (shared[t] + w0*contrib[s0] + w1*contrib[s1]) / 3   (shared already in out)
__global__ void k_combine(float* __restrict__ out, const float* __restrict__ contrib,
                          const int* __restrict__ token_slot, const float* __restrict__ topkw) {
  int t = blockIdx.x;
  int c = threadIdx.x * 4;
  int s0 = token_slot[t * 2 + 0], s1 = token_slot[t * 2 + 1];
  float w0 = topkw[t * 2 + 0], w1 = topkw[t * 2 + 1];
  float* po = out + (size_t)t * DM + c;
  const float* p0 = contrib + (size_t)s0 * DM + c;
  const float* p1 = contrib + (size_t)s1 * DM + c;
  f32x4 vo = *(f32x4*)po;
  f32x4 v0 = *(const f32x4*)p0;
  f32x4 v1 = *(const f32x4*)p1;
#pragma unroll
  for (int i = 0; i < 4; i++)
    vo[i] = (vo[i] + w0 * v0[i] + w1 * v1[i]) * (1.f / 3.f);
  *(f32x4*)po = vo;
}

// ---------------- launcher ----------------
extern "C" void kernel_launch(void* const* d_in, const int* in_sizes, int n_in,
                              void* d_out, int out_size, void* d_ws, size_t ws_size,
                              hipStream_t stream) {
  const float* x   = (const float*)d_in[0];
  const float* Wg  = (const float*)d_in[1];
  const float* Ws1 = (const float*)d_in[2];
  const float* Ws3 = (const float*)d_in[3];
  const float* Ws2 = (const float*)d_in[4];
  const float* We1 = (const float*)d_in[5];
  const float* We3 = (const float*)d_in[6];
  const float* We2 = (const float*)d_in[7];
  float* out = (float*)d_out;

  if (ws_size < WS_NEEDED) return;

  char* w = (char*)d_ws;
  unsigned short* xb   = (unsigned short*)(w + OFF_XB);
  unsigned short* wb13 = (unsigned short*)(w + OFF_WB13);
  unsigned short* wb2  = (unsigned short*)(w + OFF_WB2);
  unsigned short* H    = (unsigned short*)(w + OFF_H);
  float* contrib       = (float*)(w + OFF_CONTRIB);
  float* topkw         = (float*)(w + OFF_TOPKW);
  int* topki           = (int*)(w + OFF_TOPKI);
  int* slot_token      = (int*)(w + OFF_SLOTTOK);
  int* token_slot      = (int*)(w + OFF_TOKSLOT);
  int* offs            = (int*)(w + OFF_OFFS);

  k_gatecvt<<<TTOK / 4, 256, 0, stream>>>(x, Wg, topkw, topki, xb);
  k_route<<<1, 1024, 0, stream>>>(topki, offs, slot_token, token_slot);
  k_t13<<<dim3(FF / 64, DM / 64, 9), 256, 0, stream>>>(We1, We3, Ws1, Ws3, wb13);
  k_t2<<<dim3(DM / 64, FF / 64, 9), 256, 0, stream>>>(We2, Ws2, wb2);

  k_gemm<true, 1024, 4096><<<dim3(16, 56, 1), 512, 0, stream>>>(
      xb, wb13, H, nullptr, nullptr, slot_token, offs);
  k_gemm<false, 2048, 1024><<<dim3(4, 56, 1), 512, 0, stream>>>(
      H, wb2, nullptr, contrib, out, slot_token, offs);

  k_combine<<<TTOK, 256, 0, stream>>>(out, contrib, token_slot, topkw);
}